// Round 2
// baseline (1419.360 us; speedup 1.0000x reference)
//
#include <hip/hip_runtime.h>

// Problem constants
#define BB   4
#define CIN  64
#define HH   256
#define WW   256
#define QQ   256
#define KK   16

typedef _Float16 half8 __attribute__((ext_vector_type(8)));
typedef float   f32x4 __attribute__((ext_vector_type(4)));

// ---- workspace layout (bytes) ----
// w1r: fp16 [256][9][64]    = 294912
// w2r: fp16 [256][9][256]   = 1179648
// w3r: fp16 [256][256]      = 131072
// mu2: fp32 [16]            = 64 (padded)
// buf1: fp16 [65536][256]   = 33554432   (act1 for current batch)
// buf2: fp16 [65536][256]   = 33554432   (act0 [65536][64] first 8MiB, then act2)
#define OFF_W1R   0ull
#define OFF_W2R   294912ull
#define OFF_W3R   1474560ull
#define OFF_MU2   1605632ull
#define OFF_BUF1  1605888ull
#define OFF_BUF2  35160320ull
// total needed: 68714752 bytes (~65.5 MiB)

// ---------------------------------------------------------------------------
// Prep: reorder weights OIHW -> [o][tap][c] fp16; w3 -> [o][c] fp16; mu2[k]
// ---------------------------------------------------------------------------
__global__ __launch_bounds__(256) void k_prep(
    const float* __restrict__ w1, const float* __restrict__ w2,
    const float* __restrict__ w3, const float* __restrict__ mu,
    _Float16* __restrict__ w1r, _Float16* __restrict__ w2r,
    _Float16* __restrict__ w3r, float* __restrict__ mu2) {
  int idx = blockIdx.x * 256 + threadIdx.x;
  if (idx < 147456) {                       // w1r: [256 o][9 t][64 c]
    int o = idx / 576, rem = idx - o * 576;
    int t = rem >> 6, c = rem & 63;
    w1r[idx] = (_Float16)w1[(o * 64 + c) * 9 + t];
  } else if (idx < 147456 + 589824) {       // w2r: [256 o][9 t][256 c]
    int j = idx - 147456;
    int o = j / 2304, rem = j - o * 2304;
    int t = rem >> 8, c = rem & 255;
    w2r[j] = (_Float16)w2[(o * 256 + c) * 9 + t];
  } else if (idx < 737280 + 65536) {        // w3r: [256 o][256 c]
    int j = idx - 737280;
    w3r[j] = (_Float16)w3[j];
  } else if (idx < 802816 + 16) {           // mu2
    int k = idx - 802816;
    float s = 0.f;
    for (int c = 0; c < 256; ++c) { float v = mu[k * 256 + c]; s += v * v; }
    mu2[k] = s;
  }
}

// ---------------------------------------------------------------------------
// T0: one batch of x NCHW fp32 -> act0 [HW][64] fp16 (LDS transpose)
// grid 1024 pixel-blocks of 64
// ---------------------------------------------------------------------------
__global__ __launch_bounds__(256) void k_t0(const float* __restrict__ x,
                                            _Float16* __restrict__ act0) {
  __shared__ float tile[64][65];
  int p0 = blockIdx.x << 6;
  int t = threadIdx.x;
  {
    int p = t & 63, c0 = t >> 6;
    const float* xb = x + p0 + p;
#pragma unroll
    for (int i = 0; i < 16; ++i) {
      int c = c0 + (i << 2);
      tile[c][p] = xb[(size_t)c * 65536];
    }
  }
  __syncthreads();
  {
    int c = t & 63, p1 = t >> 6;
    _Float16* o = act0 + (size_t)p0 * CIN + c;
#pragma unroll
    for (int i = 0; i < 16; ++i) {
      int p = p1 + (i << 2);
      o[(size_t)p * CIN] = (_Float16)tile[c][p];
    }
  }
}

// ---------------------------------------------------------------------------
// Conv 3x3 (replicate pad) + bias + ReLU, implicit GEMM, fp16 MFMA.
// One batch. Workgroup: 256 thr (4 waves, 2x2), tile M=128 px (16w x 8h),
// N=128 ch. grid 1024 = tyi(5b) | txi(4b) | nblk(1b)
// ---------------------------------------------------------------------------
template <int CI>
__global__ __launch_bounds__(256) void k_conv(
    const _Float16* __restrict__ actin, const _Float16* __restrict__ wr,
    const float* __restrict__ bias, _Float16* __restrict__ actout) {
  constexpr int KROW = 9 * CI;
  __shared__ __align__(16) _Float16 As[180 * 40];  // halo 10x18 px, 32c + pad
  __shared__ __align__(16) _Float16 Bs[128 * 40];  // 128 n, 32c + pad

  int tid = threadIdx.x;
  int id = blockIdx.x;
  int nblk = id & 1; id >>= 1;
  int txi = id & 15; id >>= 4;
  int tyi = id;
  int x0 = txi << 4, y0 = tyi << 3;
  int n0 = nblk << 7;
  int lane = tid & 63, wave = tid >> 6;
  int mwave = wave >> 1, nwave = wave & 1;
  int quad = lane >> 4, l15 = lane & 15;

  f32x4 acc[4][4];
#pragma unroll
  for (int i = 0; i < 4; ++i)
#pragma unroll
    for (int j = 0; j < 4; ++j) acc[i][j] = {0.f, 0.f, 0.f, 0.f};

  bool doA = tid < 180;
  const _Float16* asrc = actin;
  if (doA) {
    int hy = tid / 18, hx = tid - hy * 18;
    int y = min(max(y0 - 1 + hy, 0), 255);
    int x = min(max(x0 - 1 + hx, 0), 255);
    asrc = actin + ((size_t)(y * 256 + x)) * CI;
  }

  for (int cc = 0; cc < CI / 32; ++cc) {
    int cbase = cc << 5;
    __syncthreads();
    if (doA) {
      const uint4* s = (const uint4*)(asrc + cbase);
      uint4* d = (uint4*)&As[tid * 40];
      d[0] = s[0]; d[1] = s[1]; d[2] = s[2]; d[3] = s[3];
    }
    for (int t = 0; t < 9; ++t) {
      if (t) __syncthreads();
      // stage B: 128 n x 32 c = 512 uint4
      {
        int i0 = tid;
        int n_ = i0 >> 2, q_ = i0 & 3;
        ((uint4*)&Bs[n_ * 40])[q_] =
            ((const uint4*)(wr + (size_t)(n0 + n_) * KROW + t * CI + cbase))[q_];
        int i1 = tid + 256;
        n_ = i1 >> 2; q_ = i1 & 3;
        ((uint4*)&Bs[n_ * 40])[q_] =
            ((const uint4*)(wr + (size_t)(n0 + n_) * KROW + t * CI + cbase))[q_];
      }
      __syncthreads();
      int dy = t / 3, dx = t - dy * 3;
      half8 af[4], bf[4];
#pragma unroll
      for (int i = 0; i < 4; ++i) {
        int pix = (mwave * 4 + i + dy) * 18 + (l15 + dx);
        af[i] = *(const half8*)&As[pix * 40 + quad * 8];
        bf[i] = *(const half8*)&Bs[(nwave * 64 + i * 16 + l15) * 40 + quad * 8];
      }
#pragma unroll
      for (int ms = 0; ms < 4; ++ms)
#pragma unroll
        for (int ns = 0; ns < 4; ++ns)
          acc[ms][ns] = __builtin_amdgcn_mfma_f32_16x16x32_f16(
              af[ms], bf[ns], acc[ms][ns], 0, 0, 0);
    }
  }

  // epilogue: bias + relu, store [HW][256] fp16
#pragma unroll
  for (int ns = 0; ns < 4; ++ns) {
    int n = n0 + nwave * 64 + ns * 16 + l15;
    float bn = bias[n];
#pragma unroll
    for (int ms = 0; ms < 4; ++ms) {
      int ty = mwave * 4 + ms;
#pragma unroll
      for (int r = 0; r < 4; ++r) {
        int tx = quad * 4 + r;
        float v = acc[ms][ns][r] + bn;
        v = fmaxf(v, 0.f);
        size_t P = (size_t)((y0 + ty) * 256 + (x0 + tx));
        actout[P * 256 + n] = (_Float16)v;
      }
    }
  }
}

// ---------------------------------------------------------------------------
// Head (one batch): 1x1 conv (GEMM M=64 px, N=256, K=256) + bias -> q fp32,
// logits = 2*q.mu_k - |mu_k|^2 (-|q|^2 is softmax-invariant), softmax over
// 16, dot with label. Two-chunk epilogue keeps LDS at 32.9 KB.
// ---------------------------------------------------------------------------
__global__ __launch_bounds__(256) void k_head(
    const _Float16* __restrict__ act2, const _Float16* __restrict__ w3r,
    const float* __restrict__ b3, const float* __restrict__ mu,
    const float* __restrict__ mu2, const float* __restrict__ label,
    float* __restrict__ out) {
  __shared__ __align__(16) char lds[32 * 257 * 4];  // 32896 B, aliased
  _Float16* As = (_Float16*)lds;            // [64*40] = 5120 B
  _Float16* Bs = (_Float16*)(lds + 5120);   // [256*40] = 20480 B
  float* Qs = (float*)lds;                  // [32][257] (epilogue phase)

  int tid = threadIdx.x;
  int p0 = blockIdx.x << 6;
  int lane = tid & 63, wave = tid >> 6;
  int quad = lane >> 4, l15 = lane & 15;

  f32x4 acc[4][4];
#pragma unroll
  for (int i = 0; i < 4; ++i)
#pragma unroll
    for (int j = 0; j < 4; ++j) acc[i][j] = {0.f, 0.f, 0.f, 0.f};

  for (int cc = 0; cc < 8; ++cc) {
    int cbase = cc << 5;
    __syncthreads();
    {
      int pix = tid >> 2, q = tid & 3;
      ((uint4*)&As[pix * 40])[q] =
          ((const uint4*)(act2 + ((size_t)(p0 + pix) << 8) + cbase))[q];
#pragma unroll
      for (int j = 0; j < 4; ++j) {
        int idx2 = tid + (j << 8);
        int n_ = idx2 >> 2, q_ = idx2 & 3;
        ((uint4*)&Bs[n_ * 40])[q_] =
            ((const uint4*)(w3r + ((size_t)n_ << 8) + cbase))[q_];
      }
    }
    __syncthreads();
    half8 af[4], bf[4];
#pragma unroll
    for (int i = 0; i < 4; ++i) {
      af[i] = *(const half8*)&As[(i * 16 + l15) * 40 + quad * 8];
      bf[i] = *(const half8*)&Bs[(wave * 64 + i * 16 + l15) * 40 + quad * 8];
    }
#pragma unroll
    for (int ms = 0; ms < 4; ++ms)
#pragma unroll
      for (int ns = 0; ns < 4; ++ns)
        acc[ms][ns] = __builtin_amdgcn_mfma_f32_16x16x32_f16(
            af[ms], bf[ns], acc[ms][ns], 0, 0, 0);
  }

  // two-chunk epilogue + fp32 head; 8 lanes per pixel, 32 channels per lane
  int pixl = tid >> 3, part = tid & 7;
  for (int ch = 0; ch < 2; ++ch) {
    __syncthreads();   // GEMM done / previous chunk's Qs reads done
#pragma unroll
    for (int msl = 0; msl < 2; ++msl) {
      int ms = ch * 2 + msl;
#pragma unroll
      for (int ns = 0; ns < 4; ++ns) {
        int n = wave * 64 + ns * 16 + l15;
        float bn = b3[n];
#pragma unroll
        for (int r = 0; r < 4; ++r) {
          int prow = msl * 16 + quad * 4 + r;
          Qs[prow * 257 + n] = acc[ms][ns][r] + bn;
        }
      }
    }
    __syncthreads();
    float cross[16];
#pragma unroll
    for (int k = 0; k < 16; ++k) cross[k] = 0.f;
#pragma unroll
    for (int i = 0; i < 8; ++i) {
      // stagger so the 8 parts of a pixel start 4 banks apart (<=2-way)
      int c4 = (part << 5) + (((i + part) << 2) & 31);
      const float* qp = &Qs[pixl * 257 + c4];
      float q0 = qp[0], q1 = qp[1], q2 = qp[2], q3 = qp[3];
#pragma unroll
      for (int k = 0; k < 16; ++k) {
        const float4 m4 = *(const float4*)(mu + (k << 8) + c4);
        cross[k] = fmaf(q0, m4.x,
                   fmaf(q1, m4.y, fmaf(q2, m4.z, fmaf(q3, m4.w, cross[k]))));
      }
    }
#pragma unroll
    for (int k = 0; k < 16; ++k) {
      cross[k] += __shfl_xor(cross[k], 1, 64);
      cross[k] += __shfl_xor(cross[k], 2, 64);
      cross[k] += __shfl_xor(cross[k], 4, 64);
    }
    float mx = -1e30f;
    float lg[16];
#pragma unroll
    for (int k = 0; k < 16; ++k) {
      lg[k] = 2.f * cross[k] - mu2[k];
      mx = fmaxf(mx, lg[k]);
    }
    float num = 0.f, den = 0.f;
#pragma unroll
    for (int k = 0; k < 16; ++k) {
      float e = __expf(lg[k] - mx);
      num += e * label[k];
      den += e;
    }
    if (part == 0) out[p0 + (ch << 5) + pixl] = num / den;
  }
}

// ---------------------------------------------------------------------------
extern "C" void kernel_launch(void* const* d_in, const int* in_sizes, int n_in,
                              void* d_out, int out_size, void* d_ws, size_t ws_size,
                              hipStream_t stream) {
  const float* x  = (const float*)d_in[0];
  const float* w1 = (const float*)d_in[1];
  const float* b1 = (const float*)d_in[2];
  const float* w2 = (const float*)d_in[3];
  const float* b2 = (const float*)d_in[4];
  const float* w3 = (const float*)d_in[5];
  const float* b3 = (const float*)d_in[6];
  const float* mu = (const float*)d_in[7];
  const float* label = (const float*)d_in[8];
  float* out = (float*)d_out;

  char* ws = (char*)d_ws;
  _Float16* w1r  = (_Float16*)(ws + OFF_W1R);
  _Float16* w2r  = (_Float16*)(ws + OFF_W2R);
  _Float16* w3r  = (_Float16*)(ws + OFF_W3R);
  float*    mu2  = (float*)   (ws + OFF_MU2);
  _Float16* buf1 = (_Float16*)(ws + OFF_BUF1);   // act1 (current batch)
  _Float16* buf2 = (_Float16*)(ws + OFF_BUF2);   // act0 then act2

  k_prep<<<3137, 256, 0, stream>>>(w1, w2, w3, mu, w1r, w2r, w3r, mu2);
  for (int b = 0; b < BB; ++b) {
    k_t0<<<1024, 256, 0, stream>>>(x + (size_t)b * CIN * 65536, buf2);
    k_conv<64><<<1024, 256, 0, stream>>>(buf2, w1r, b1, buf1);
    k_conv<256><<<1024, 256, 0, stream>>>(buf1, w2r, b2, buf2);
    k_head<<<1024, 256, 0, stream>>>(buf2, w3r, b3, mu, mu2, label,
                                     out + (size_t)b * 65536);
  }
}

// Round 3
// 903.733 us; speedup vs baseline: 1.5706x; 1.5706x over previous
//
#include <hip/hip_runtime.h>

// Problem constants
#define BB   4
#define CIN  64
#define HH   256
#define WW   256
#define QQ   256
#define KK   16

typedef _Float16 half8 __attribute__((ext_vector_type(8)));
typedef float   f32x4 __attribute__((ext_vector_type(4)));

// ---- workspace layout (bytes) ----
// w1r:  fp16 [256][9][64]   = 294912
// w2r:  fp16 [256][9][256]  = 1179648
// wmu2: fp32 [16][256]      = 16384   (2 * mu . W3, head folded)
// lgb:  fp32 [16]           = 64      (2*mu.b3 - |mu|^2)
// buf1: fp16 [65536][256]   = 33554432  (act1, current batch)
// buf2: fp16 [65536][256]   = 33554432  (act0 [65536][64] first 8MiB, then act2)
#define OFF_W1R   0ull
#define OFF_W2R   294912ull
#define OFF_WMU   1474560ull
#define OFF_LGB   1490944ull
#define OFF_BUF1  1605888ull
#define OFF_BUF2  35160320ull
// total needed: 68714752 bytes (~65.5 MiB)

// ---------------------------------------------------------------------------
// Prep: reorder conv weights OIHW -> [o][tap][c] fp16; fold head:
// wmu2[k][c] = 2 * sum_o mu[k][o]*w3[o][c];  lgb[k] = 2*mu_k.b3 - |mu_k|^2
// ---------------------------------------------------------------------------
__global__ __launch_bounds__(256) void k_prep(
    const float* __restrict__ w1, const float* __restrict__ w2,
    const float* __restrict__ w3, const float* __restrict__ b3,
    const float* __restrict__ mu,
    _Float16* __restrict__ w1r, _Float16* __restrict__ w2r,
    float* __restrict__ wmu2, float* __restrict__ lgb) {
  int idx = blockIdx.x * 256 + threadIdx.x;
  if (idx < 147456) {                       // w1r: [256 o][9 t][64 c]
    int o = idx / 576, rem = idx - o * 576;
    int t = rem >> 6, c = rem & 63;
    w1r[idx] = (_Float16)w1[(o * 64 + c) * 9 + t];
  } else if (idx < 737280) {                // w2r: [256 o][9 t][256 c]
    int j = idx - 147456;
    int o = j / 2304, rem = j - o * 2304;
    int t = rem >> 8, c = rem & 255;
    w2r[j] = (_Float16)w2[(o * 256 + c) * 9 + t];
  } else if (idx < 741376) {                // wmu2: [16 k][256 c]
    int j = idx - 737280;
    int k = j >> 8, c = j & 255;
    float s = 0.f;
    for (int o = 0; o < 256; ++o) s = fmaf(mu[k * 256 + o], w3[o * 256 + c], s);
    wmu2[j] = 2.f * s;
  } else if (idx < 741392) {                // lgb: [16]
    int k = idx - 741376;
    float s1 = 0.f, s2 = 0.f;
    for (int o = 0; o < 256; ++o) {
      float m = mu[k * 256 + o];
      s1 = fmaf(m, b3[o], s1);
      s2 = fmaf(m, m, s2);
    }
    lgb[k] = 2.f * s1 - s2;
  }
}

// ---------------------------------------------------------------------------
// T0: one batch of x NCHW fp32 -> act0 [HW][64] fp16 (LDS transpose)
// ---------------------------------------------------------------------------
__global__ __launch_bounds__(256) void k_t0(const float* __restrict__ x,
                                            _Float16* __restrict__ act0) {
  __shared__ float tile[64][65];
  int p0 = blockIdx.x << 6;
  int t = threadIdx.x;
  {
    int p = t & 63, c0 = t >> 6;
    const float* xb = x + p0 + p;
#pragma unroll
    for (int i = 0; i < 16; ++i) {
      int c = c0 + (i << 2);
      tile[c][p] = xb[(size_t)c * 65536];
    }
  }
  __syncthreads();
  {
    int c = t & 63, p1 = t >> 6;
    _Float16* o = act0 + (size_t)p0 * CIN + c;
#pragma unroll
    for (int i = 0; i < 16; ++i) {
      int p = p1 + (i << 2);
      o[(size_t)p * CIN] = (_Float16)tile[c][p];
    }
  }
}

// ---------------------------------------------------------------------------
// Conv 3x3 (replicate pad) + bias + ReLU, implicit GEMM, fp16 MFMA.
// One batch. Workgroup: 256 thr (4 waves, 2x2), tile M=128 px (16w x 8h),
// N=128 ch. grid 1024 = tyi(5b) | txi(4b) | nblk(1b)
// ---------------------------------------------------------------------------
template <int CI>
__global__ __launch_bounds__(256) void k_conv(
    const _Float16* __restrict__ actin, const _Float16* __restrict__ wr,
    const float* __restrict__ bias, _Float16* __restrict__ actout) {
  constexpr int KROW = 9 * CI;
  __shared__ __align__(16) _Float16 As[180 * 40];  // halo 10x18 px, 32c + pad
  __shared__ __align__(16) _Float16 Bs[128 * 40];  // 128 n, 32c + pad

  int tid = threadIdx.x;
  int id = blockIdx.x;
  int nblk = id & 1; id >>= 1;
  int txi = id & 15; id >>= 4;
  int tyi = id;
  int x0 = txi << 4, y0 = tyi << 3;
  int n0 = nblk << 7;
  int lane = tid & 63, wave = tid >> 6;
  int mwave = wave >> 1, nwave = wave & 1;
  int quad = lane >> 4, l15 = lane & 15;

  f32x4 acc[4][4];
#pragma unroll
  for (int i = 0; i < 4; ++i)
#pragma unroll
    for (int j = 0; j < 4; ++j) acc[i][j] = {0.f, 0.f, 0.f, 0.f};

  bool doA = tid < 180;
  const _Float16* asrc = actin;
  if (doA) {
    int hy = tid / 18, hx = tid - hy * 18;
    int y = min(max(y0 - 1 + hy, 0), 255);
    int x = min(max(x0 - 1 + hx, 0), 255);
    asrc = actin + ((size_t)(y * 256 + x)) * CI;
  }

  for (int cc = 0; cc < CI / 32; ++cc) {
    int cbase = cc << 5;
    __syncthreads();
    if (doA) {
      const uint4* s = (const uint4*)(asrc + cbase);
      uint4* d = (uint4*)&As[tid * 40];
      d[0] = s[0]; d[1] = s[1]; d[2] = s[2]; d[3] = s[3];
    }
    for (int t = 0; t < 9; ++t) {
      if (t) __syncthreads();
      // stage B: 128 n x 32 c = 512 uint4
      {
        int i0 = tid;
        int n_ = i0 >> 2, q_ = i0 & 3;
        ((uint4*)&Bs[n_ * 40])[q_] =
            ((const uint4*)(wr + (size_t)(n0 + n_) * KROW + t * CI + cbase))[q_];
        int i1 = tid + 256;
        n_ = i1 >> 2; q_ = i1 & 3;
        ((uint4*)&Bs[n_ * 40])[q_] =
            ((const uint4*)(wr + (size_t)(n0 + n_) * KROW + t * CI + cbase))[q_];
      }
      __syncthreads();
      int dy = t / 3, dx = t - dy * 3;
      half8 af[4], bf[4];
#pragma unroll
      for (int i = 0; i < 4; ++i) {
        int pix = (mwave * 4 + i + dy) * 18 + (l15 + dx);
        af[i] = *(const half8*)&As[pix * 40 + quad * 8];
        bf[i] = *(const half8*)&Bs[(nwave * 64 + i * 16 + l15) * 40 + quad * 8];
      }
#pragma unroll
      for (int ms = 0; ms < 4; ++ms)
#pragma unroll
        for (int ns = 0; ns < 4; ++ns)
          acc[ms][ns] = __builtin_amdgcn_mfma_f32_16x16x32_f16(
              af[ms], bf[ns], acc[ms][ns], 0, 0, 0);
    }
  }

  // epilogue: bias + relu, store [HW][256] fp16
#pragma unroll
  for (int ns = 0; ns < 4; ++ns) {
    int n = n0 + nwave * 64 + ns * 16 + l15;
    float bn = bias[n];
#pragma unroll
    for (int ms = 0; ms < 4; ++ms) {
      int ty = mwave * 4 + ms;
#pragma unroll
      for (int r = 0; r < 4; ++r) {
        int tx = quad * 4 + r;
        float v = acc[ms][ns][r] + bn;
        v = fmaxf(v, 0.f);
        size_t P = (size_t)((y0 + ty) * 256 + (x0 + tx));
        actout[P * 256 + n] = (_Float16)v;
      }
    }
  }
}

// ---------------------------------------------------------------------------
// Head (one batch): logit_k(px) = wmu2_k . act2[px] + lgb[k]; softmax over
// 16; dot with label. One pixel per thread, all fp32 VALU. wmu2/lgb/label
// reads are wave-uniform -> scalar loads (constant cache), no LDS.
// ---------------------------------------------------------------------------
__global__ __launch_bounds__(256) void k_head(
    const _Float16* __restrict__ act2, const float* __restrict__ wmu2,
    const float* __restrict__ lgb, const float* __restrict__ label,
    float* __restrict__ out) {
  int px = blockIdx.x * 256 + threadIdx.x;
  const half8* ap = (const half8*)(act2 + ((size_t)px << 8));
  float cr[16];
#pragma unroll
  for (int k = 0; k < 16; ++k) cr[k] = lgb[k];
#pragma unroll 2
  for (int cc = 0; cc < 32; ++cc) {
    half8 h = ap[cc];
    float a0 = (float)h[0], a1 = (float)h[1], a2 = (float)h[2],
          a3 = (float)h[3], a4 = (float)h[4], a5 = (float)h[5],
          a6 = (float)h[6], a7 = (float)h[7];
#pragma unroll
    for (int k = 0; k < 16; ++k) {
      const float* w = wmu2 + (k << 8) + (cc << 3);
      float c0 = cr[k];
      c0 = fmaf(a0, w[0], c0);
      c0 = fmaf(a1, w[1], c0);
      c0 = fmaf(a2, w[2], c0);
      c0 = fmaf(a3, w[3], c0);
      c0 = fmaf(a4, w[4], c0);
      c0 = fmaf(a5, w[5], c0);
      c0 = fmaf(a6, w[6], c0);
      c0 = fmaf(a7, w[7], c0);
      cr[k] = c0;
    }
  }
  float mx = cr[0];
#pragma unroll
  for (int k = 1; k < 16; ++k) mx = fmaxf(mx, cr[k]);
  float num = 0.f, den = 0.f;
#pragma unroll
  for (int k = 0; k < 16; ++k) {
    float e = __expf(cr[k] - mx);
    num = fmaf(e, label[k], num);
    den += e;
  }
  out[px] = num / den;
}

// ---------------------------------------------------------------------------
extern "C" void kernel_launch(void* const* d_in, const int* in_sizes, int n_in,
                              void* d_out, int out_size, void* d_ws, size_t ws_size,
                              hipStream_t stream) {
  const float* x  = (const float*)d_in[0];
  const float* w1 = (const float*)d_in[1];
  const float* b1 = (const float*)d_in[2];
  const float* w2 = (const float*)d_in[3];
  const float* b2 = (const float*)d_in[4];
  const float* w3 = (const float*)d_in[5];
  const float* b3 = (const float*)d_in[6];
  const float* mu = (const float*)d_in[7];
  const float* label = (const float*)d_in[8];
  float* out = (float*)d_out;

  char* ws = (char*)d_ws;
  _Float16* w1r  = (_Float16*)(ws + OFF_W1R);
  _Float16* w2r  = (_Float16*)(ws + OFF_W2R);
  float*    wmu2 = (float*)   (ws + OFF_WMU);
  float*    lgb  = (float*)   (ws + OFF_LGB);
  _Float16* buf1 = (_Float16*)(ws + OFF_BUF1);   // act1 (current batch)
  _Float16* buf2 = (_Float16*)(ws + OFF_BUF2);   // act0 then act2

  k_prep<<<2897, 256, 0, stream>>>(w1, w2, w3, b3, mu, w1r, w2r, wmu2, lgb);
  for (int b = 0; b < BB; ++b) {
    k_t0<<<1024, 256, 0, stream>>>(x + (size_t)b * CIN * 65536, buf2);
    k_conv<64><<<1024, 256, 0, stream>>>(buf2, w1r, b1, buf1);
    k_conv<256><<<1024, 256, 0, stream>>>(buf1, w2r, b2, buf2);
    k_head<<<256, 256, 0, stream>>>(buf2, wmu2, lgb, label,
                                    out + (size_t)b * 65536);
  }
}

// Round 4
// 889.936 us; speedup vs baseline: 1.5949x; 1.0155x over previous
//
#include <hip/hip_runtime.h>

// Problem constants
#define BB   4
#define CIN  64
#define HH   256
#define WW   256
#define QQ   256
#define KK   16

typedef _Float16 half8 __attribute__((ext_vector_type(8)));
typedef float   f32x4 __attribute__((ext_vector_type(4)));

// ---- workspace layout (bytes) ----
#define OFF_W1R   0ull
#define OFF_W2R   294912ull
#define OFF_WMU   1474560ull
#define OFF_LGB   1490944ull
#define OFF_BUF1  1605888ull
#define OFF_BUF2  35160320ull
// total needed: 68714752 bytes (~65.5 MiB)

// ---------------------------------------------------------------------------
// Prep: reorder conv weights OIHW -> [o][tap][c] fp16; fold head:
// wmu2[k][c] = 2 * sum_o mu[k][o]*w3[o][c];  lgb[k] = 2*mu_k.b3 - |mu_k|^2
// ---------------------------------------------------------------------------
__global__ __launch_bounds__(256) void k_prep(
    const float* __restrict__ w1, const float* __restrict__ w2,
    const float* __restrict__ w3, const float* __restrict__ b3,
    const float* __restrict__ mu,
    _Float16* __restrict__ w1r, _Float16* __restrict__ w2r,
    float* __restrict__ wmu2, float* __restrict__ lgb) {
  int idx = blockIdx.x * 256 + threadIdx.x;
  if (idx < 147456) {                       // w1r: [256 o][9 t][64 c]
    int o = idx / 576, rem = idx - o * 576;
    int t = rem >> 6, c = rem & 63;
    w1r[idx] = (_Float16)w1[(o * 64 + c) * 9 + t];
  } else if (idx < 737280) {                // w2r: [256 o][9 t][256 c]
    int j = idx - 147456;
    int o = j / 2304, rem = j - o * 2304;
    int t = rem >> 8, c = rem & 255;
    w2r[j] = (_Float16)w2[(o * 256 + c) * 9 + t];
  } else if (idx < 741376) {                // wmu2: [16 k][256 c]
    int j = idx - 737280;
    int k = j >> 8, c = j & 255;
    float s = 0.f;
    for (int o = 0; o < 256; ++o) s = fmaf(mu[k * 256 + o], w3[o * 256 + c], s);
    wmu2[j] = 2.f * s;
  } else if (idx < 741392) {                // lgb: [16]
    int k = idx - 741376;
    float s1 = 0.f, s2 = 0.f;
    for (int o = 0; o < 256; ++o) {
      float m = mu[k * 256 + o];
      s1 = fmaf(m, b3[o], s1);
      s2 = fmaf(m, m, s2);
    }
    lgb[k] = 2.f * s1 - s2;
  }
}

// ---------------------------------------------------------------------------
// T0: one batch of x NCHW fp32 -> act0 [HW][64] fp16 (LDS transpose)
// ---------------------------------------------------------------------------
__global__ __launch_bounds__(256) void k_t0(const float* __restrict__ x,
                                            _Float16* __restrict__ act0) {
  __shared__ float tile[64][65];
  int p0 = blockIdx.x << 6;
  int t = threadIdx.x;
  {
    int p = t & 63, c0 = t >> 6;
    const float* xb = x + p0 + p;
#pragma unroll
    for (int i = 0; i < 16; ++i) {
      int c = c0 + (i << 2);
      tile[c][p] = xb[(size_t)c * 65536];
    }
  }
  __syncthreads();
  {
    int c = t & 63, p1 = t >> 6;
    _Float16* o = act0 + (size_t)p0 * CIN + c;
#pragma unroll
    for (int i = 0; i < 16; ++i) {
      int p = p1 + (i << 2);
      o[(size_t)p * CIN] = (_Float16)tile[c][p];
    }
  }
}

// ---------------------------------------------------------------------------
// Conv 3x3 (replicate pad) + bias + ReLU, implicit GEMM, fp16 MFMA.
// Software-pipelined: Bs double-buffered, B prefetched 2 taps deep into
// registers, 1 barrier per tap. A-tile register-prefetched across cc-chunks.
// Workgroup: 256 thr (4 waves, 2x2), tile M=128 px (16w x 8h), N=128 ch.
// grid 1024 = tyi(5b) | txi(4b) | nblk(1b)
// ---------------------------------------------------------------------------
template <int CI>
__global__ __launch_bounds__(256) void k_conv(
    const _Float16* __restrict__ actin, const _Float16* __restrict__ wr,
    const float* __restrict__ bias, _Float16* __restrict__ actout) {
  constexpr int KROW = 9 * CI;
  constexpr int NC = CI / 32;
  constexpr int NT = 9 * NC;
  __shared__ __align__(16) _Float16 As[180 * 40];     // 14400 B
  __shared__ __align__(16) _Float16 Bs[2][128 * 40];  // 2 x 10240 B

  int tid = threadIdx.x;
  int id = blockIdx.x;
  int nblk = id & 1; id >>= 1;
  int txi = id & 15; id >>= 4;
  int tyi = id;
  int x0 = txi << 4, y0 = tyi << 3;
  int n0 = nblk << 7;
  int lane = tid & 63, wave = tid >> 6;
  int mwave = wave >> 1, nwave = wave & 1;
  int quad = lane >> 4, l15 = lane & 15;

  f32x4 acc[4][4];
#pragma unroll
  for (int i = 0; i < 4; ++i)
#pragma unroll
    for (int j = 0; j < 4; ++j) acc[i][j] = {0.f, 0.f, 0.f, 0.f};

  bool doA = tid < 180;
  const _Float16* asrc = actin;
  if (doA) {
    int hy = tid / 18, hx = tid - hy * 18;
    int y = min(max(y0 - 1 + hy, 0), 255);
    int x = min(max(x0 - 1 + hx, 0), 255);
    asrc = actin + ((size_t)(y * 256 + x)) * CI;
  }

  // B staging: thread handles rows (tid>>2) and (tid>>2)+64, quarter tid&3
  const _Float16* bsrc = wr + (size_t)(n0 + (tid >> 2)) * KROW + (tid & 3) * 8;
  const size_t brow64 = (size_t)64 * KROW;

  uint4 s0a, s0b, s1a, s1b, ar[4];

  auto ldB = [&](int j, uint4& pa, uint4& pb) {
    int tt = j % 9, ccx = j / 9;
    int off = tt * CI + ccx * 32;
    pa = *(const uint4*)(bsrc + off);
    pb = *(const uint4*)(bsrc + brow64 + off);
  };
  auto stB = [&](int sb, const uint4& pa, const uint4& pb) {
    ((uint4*)&Bs[sb][(tid >> 2) * 40])[tid & 3] = pa;
    ((uint4*)&Bs[sb][((tid >> 2) + 64) * 40])[tid & 3] = pb;
  };
  auto ldA = [&](int ccx) {
    const uint4* sp = (const uint4*)(asrc + (ccx << 5));
    ar[0] = sp[0]; ar[1] = sp[1]; ar[2] = sp[2]; ar[3] = sp[3];
  };
  auto stA = [&]() {
    uint4* d = (uint4*)&As[tid * 40];
    d[0] = ar[0]; d[1] = ar[1]; d[2] = ar[2]; d[3] = ar[3];
  };

  // Prologue: stage B(0), A(0); prefetch B(1),B(2) and A(1) into registers.
  ldB(0, s0a, s0b);
  if (doA) ldA(0);
  stB(0, s0a, s0b);
  if (doA) stA();
  ldB(1, s0a, s0b);                 // slot0 <- B(1)
  ldB(2 < NT ? 2 : NT - 1, s1a, s1b);  // slot1 <- B(2)
  if (doA) ldA(NC > 1 ? 1 : 0);
  __syncthreads();

  for (int cc = 0; cc < NC; ++cc) {
#pragma unroll
    for (int t = 0; t < 9; ++t) {
      int j = cc * 9 + t;
      int sb = j & 1;
      int dy = t / 3, dx = t - dy * 3;
      half8 af[4], bf[4];
#pragma unroll
      for (int i = 0; i < 4; ++i) {
        int pix = (mwave * 4 + i + dy) * 18 + (l15 + dx);
        af[i] = *(const half8*)&As[pix * 40 + quad * 8];
        bf[i] = *(const half8*)&Bs[sb][(nwave * 64 + i * 16 + l15) * 40 + quad * 8];
      }
#pragma unroll
      for (int ms = 0; ms < 4; ++ms)
#pragma unroll
        for (int ns = 0; ns < 4; ++ns)
          acc[ms][ns] = __builtin_amdgcn_mfma_f32_16x16x32_f16(
              af[ms], bf[ns], acc[ms][ns], 0, 0, 0);
      if (j + 1 < NT) {
        int jn = j + 3 < NT ? j + 3 : NT - 1;
        if (sb == 0) { stB(1, s0a, s0b); ldB(jn, s0a, s0b); }
        else         { stB(0, s1a, s1b); ldB(jn, s1a, s1b); }
        if (t == 8) {
          __syncthreads();             // all waves done reading As for this cc
          if (doA) { stA(); ldA(cc + 2 < NC ? cc + 2 : NC - 1); }
        }
        __syncthreads();
      }
    }
  }

  // epilogue: bias + relu, store [HW][256] fp16
#pragma unroll
  for (int ns = 0; ns < 4; ++ns) {
    int n = n0 + nwave * 64 + ns * 16 + l15;
    float bn = bias[n];
#pragma unroll
    for (int ms = 0; ms < 4; ++ms) {
      int ty = mwave * 4 + ms;
#pragma unroll
      for (int r = 0; r < 4; ++r) {
        int tx = quad * 4 + r;
        float v = acc[ms][ns][r] + bn;
        v = fmaxf(v, 0.f);
        size_t P = (size_t)((y0 + ty) * 256 + (x0 + tx));
        actout[P * 256 + n] = (_Float16)v;
      }
    }
  }
}

// ---------------------------------------------------------------------------
// Head (one batch): logit_k(px) = wmu2_k . act2[px] + lgb[k]; softmax over
// 16; dot with label. One pixel per thread, all fp32 VALU.
// ---------------------------------------------------------------------------
__global__ __launch_bounds__(256) void k_head(
    const _Float16* __restrict__ act2, const float* __restrict__ wmu2,
    const float* __restrict__ lgb, const float* __restrict__ label,
    float* __restrict__ out) {
  int px = blockIdx.x * 256 + threadIdx.x;
  const half8* ap = (const half8*)(act2 + ((size_t)px << 8));
  float cr[16];
#pragma unroll
  for (int k = 0; k < 16; ++k) cr[k] = lgb[k];
#pragma unroll 2
  for (int cc = 0; cc < 32; ++cc) {
    half8 h = ap[cc];
    float a0 = (float)h[0], a1 = (float)h[1], a2 = (float)h[2],
          a3 = (float)h[3], a4 = (float)h[4], a5 = (float)h[5],
          a6 = (float)h[6], a7 = (float)h[7];
#pragma unroll
    for (int k = 0; k < 16; ++k) {
      const float* w = wmu2 + (k << 8) + (cc << 3);
      float c0 = cr[k];
      c0 = fmaf(a0, w[0], c0);
      c0 = fmaf(a1, w[1], c0);
      c0 = fmaf(a2, w[2], c0);
      c0 = fmaf(a3, w[3], c0);
      c0 = fmaf(a4, w[4], c0);
      c0 = fmaf(a5, w[5], c0);
      c0 = fmaf(a6, w[6], c0);
      c0 = fmaf(a7, w[7], c0);
      cr[k] = c0;
    }
  }
  float mx = cr[0];
#pragma unroll
  for (int k = 1; k < 16; ++k) mx = fmaxf(mx, cr[k]);
  float num = 0.f, den = 0.f;
#pragma unroll
  for (int k = 0; k < 16; ++k) {
    float e = __expf(cr[k] - mx);
    num = fmaf(e, label[k], num);
    den += e;
  }
  out[px] = num / den;
}

// ---------------------------------------------------------------------------
extern "C" void kernel_launch(void* const* d_in, const int* in_sizes, int n_in,
                              void* d_out, int out_size, void* d_ws, size_t ws_size,
                              hipStream_t stream) {
  const float* x  = (const float*)d_in[0];
  const float* w1 = (const float*)d_in[1];
  const float* b1 = (const float*)d_in[2];
  const float* w2 = (const float*)d_in[3];
  const float* b2 = (const float*)d_in[4];
  const float* w3 = (const float*)d_in[5];
  const float* b3 = (const float*)d_in[6];
  const float* mu = (const float*)d_in[7];
  const float* label = (const float*)d_in[8];
  float* out = (float*)d_out;

  char* ws = (char*)d_ws;
  _Float16* w1r  = (_Float16*)(ws + OFF_W1R);
  _Float16* w2r  = (_Float16*)(ws + OFF_W2R);
  float*    wmu2 = (float*)   (ws + OFF_WMU);
  float*    lgb  = (float*)   (ws + OFF_LGB);
  _Float16* buf1 = (_Float16*)(ws + OFF_BUF1);   // act1 (current batch)
  _Float16* buf2 = (_Float16*)(ws + OFF_BUF2);   // act0 then act2

  k_prep<<<2897, 256, 0, stream>>>(w1, w2, w3, b3, mu, w1r, w2r, wmu2, lgb);
  for (int b = 0; b < BB; ++b) {
    k_t0<<<1024, 256, 0, stream>>>(x + (size_t)b * CIN * 65536, buf2);
    k_conv<64><<<1024, 256, 0, stream>>>(buf2, w1r, b1, buf1);
    k_conv<256><<<1024, 256, 0, stream>>>(buf1, w2r, b2, buf2);
    k_head<<<256, 256, 0, stream>>>(buf2, wmu2, lgb, label,
                                    out + (size_t)b * 65536);
  }
}